// Round 7
// baseline (176.880 us; speedup 1.0000x reference)
//
#include <hip/hip_runtime.h>

#define NFEAT 256
#define NHID  128

#define NBK   391     // node buckets of 256 nodes (ceil(100000/256))
#define EPB   4096    // edges per block in hist/scatter passes
#define NBLK  391     // edge blocks (ceil(1600000/4096))

typedef __bf16 bf16x8 __attribute__((ext_vector_type(8)));
typedef __bf16 bf16x4 __attribute__((ext_vector_type(4)));
typedef float  f32x4  __attribute__((ext_vector_type(4)));

// ---------------------------------------------------------------------------
// 1) Spectral norm: one power iteration -> scal[0] = 1/sigma
// ---------------------------------------------------------------------------
__global__ __launch_bounds__(256) void sigma_kernel(const float* __restrict__ W,
                                                    const float* __restrict__ u,
                                                    float* __restrict__ scal) {
    __shared__ float v[NHID];
    __shared__ float red[256];
    int tid = threadIdx.x;

    float t = 0.f;
    if (tid < NHID) {
        for (int i = 0; i < NFEAT; ++i) t += W[i * NHID + tid] * u[i];
    }
    red[tid] = (tid < NHID) ? t * t : 0.f;
    __syncthreads();
    for (int s = 128; s > 0; s >>= 1) {
        if (tid < s) red[tid] += red[tid + s];
        __syncthreads();
    }
    float nv = sqrtf(red[0]);
    float inv_nv = 1.f / (nv + 1e-12f);
    __syncthreads();
    if (tid < NHID) v[tid] = t * inv_nv;
    __syncthreads();

    float wv = 0.f;
    for (int j = 0; j < NHID; ++j) wv += W[tid * NHID + j] * v[j];
    red[tid] = wv * wv;
    __syncthreads();
    for (int s = 128; s > 0; s >>= 1) {
        if (tid < s) red[tid] += red[tid + s];
        __syncthreads();
    }
    if (tid == 0) {
        float n2  = red[0];
        float nwv = sqrtf(n2);
        float sigma = n2 / (nwv + 1e-12f);
        scal[0] = 1.f / sigma;
    }
}

// ---------------------------------------------------------------------------
// 2) W^T in bf16, scaled by 1/sigma
// ---------------------------------------------------------------------------
__global__ __launch_bounds__(256) void wt_kernel(const float* __restrict__ W,
                                                 const float* __restrict__ scal,
                                                 __bf16* __restrict__ WT) {
    int idx = blockIdx.x * 256 + threadIdx.x;
    int c = idx >> 8;
    int r = idx & 255;
    WT[c * NFEAT + r] = (__bf16)(W[r * NHID + c] * scal[0]);
}

// ---------------------------------------------------------------------------
// 3) C1: per-block histogram over coarse buckets (bucket = dst >> 8)
// ---------------------------------------------------------------------------
__global__ __launch_bounds__(256) void hist_kernel(const int* __restrict__ ecol,
                                                   int* __restrict__ blkhist, int E) {
    __shared__ int hist[NBK];
    int tid = threadIdx.x, b = blockIdx.x;
    for (int k = tid; k < NBK; k += 256) hist[k] = 0;
    __syncthreads();
    int e0 = b * EPB;
#pragma unroll
    for (int j = 0; j < 16; ++j) {
        int idx = e0 + j * 256 + tid;
        if (idx < E) atomicAdd(&hist[ecol[idx] >> 8], 1);
    }
    __syncthreads();
    for (int k = tid; k < NBK; k += 256) blkhist[k * NBLK + b] = hist[k];
}

// ---------------------------------------------------------------------------
// 4) C3a: exclusive scan of each blkhist row (one wave per bucket) + row total
// ---------------------------------------------------------------------------
__global__ __launch_bounds__(256) void scan_rows_kernel(int* __restrict__ blkhist,
                                                        int* __restrict__ btot) {
    int k = blockIdx.x * 4 + (threadIdx.x >> 6);
    int lane = threadIdx.x & 63;
    if (k >= NBK) return;
    int carry = 0;
    for (int c0 = 0; c0 < NBLK; c0 += 64) {
        int b = c0 + lane;
        int v = (b < NBLK) ? blkhist[k * NBLK + b] : 0;
        int orig = v;
#pragma unroll
        for (int d = 1; d < 64; d <<= 1) {
            int t = __shfl_up(v, (unsigned)d, 64);
            if (lane >= d) v += t;
        }
        if (b < NBLK) blkhist[k * NBLK + b] = carry + v - orig;   // exclusive
        carry += __shfl(v, 63, 64);
    }
    if (lane == 0) btot[k] = carry;
}

// ---------------------------------------------------------------------------
// 5) C3b: exclusive scan of bucket totals -> bucket_base[0..NBK]
// ---------------------------------------------------------------------------
__global__ __launch_bounds__(512) void scan_buckets_kernel(const int* __restrict__ btot,
                                                           int* __restrict__ bbase) {
    __shared__ int s[512];
    int tid = threadIdx.x;
    int v = (tid < NBK) ? btot[tid] : 0;
    s[tid] = v;
    __syncthreads();
    int val = v;
    for (int off = 1; off < 512; off <<= 1) {
        int t = (tid >= off) ? s[tid - off] : 0;
        __syncthreads();
        val += t;
        s[tid] = val;
        __syncthreads();
    }
    if (tid <= NBK) bbase[tid] = val - v;   // tid==NBK (v=0) -> total
}

// ---------------------------------------------------------------------------
// 6) C4: coarse scatter — LDS-reorder 4096 edges by bucket, write segments
// ---------------------------------------------------------------------------
__global__ __launch_bounds__(512) void coarse_scatter_kernel(const int* __restrict__ erow,
                                                             const int* __restrict__ ecol,
                                                             const int* __restrict__ blkhist,
                                                             const int* __restrict__ bbase,
                                                             unsigned int* __restrict__ rbuf,
                                                             int E) {
    __shared__ unsigned int rec[EPB];
    __shared__ unsigned short bk[EPB];
    __shared__ int hist[NBK], sc[512], lbase[NBK], lfill[NBK], gb[NBK];
    int tid = threadIdx.x, b = blockIdx.x;
    for (int k = tid; k < NBK; k += 512) { hist[k] = 0; lfill[k] = 0; }
    __syncthreads();
    int e0 = b * EPB;
    unsigned int rv[8];
    int kv[8];
#pragma unroll
    for (int j = 0; j < 8; ++j) {
        int idx = e0 + j * 512 + tid;
        if (idx < E) {
            int c = ecol[idx];
            int s = erow[idx];
            int k = c >> 8;
            kv[j] = k;
            rv[j] = ((unsigned int)(c & 255) << 24) | (unsigned int)s;
            atomicAdd(&hist[k], 1);
        } else kv[j] = -1;
    }
    __syncthreads();
    int hv = (tid < NBK) ? hist[tid] : 0;
    sc[tid] = hv;
    __syncthreads();
    int val = hv;
    for (int off = 1; off < 512; off <<= 1) {
        int t = (tid >= off) ? sc[tid - off] : 0;
        __syncthreads();
        val += t;
        sc[tid] = val;
        __syncthreads();
    }
    if (tid < NBK) {
        lbase[tid] = val - hv;
        gb[tid] = bbase[tid] + blkhist[tid * NBLK + b];
    }
    __syncthreads();
#pragma unroll
    for (int j = 0; j < 8; ++j) {
        if (kv[j] >= 0) {
            int p = lbase[kv[j]] + atomicAdd(&lfill[kv[j]], 1);
            rec[p] = rv[j];
            bk[p] = (unsigned short)kv[j];
        }
    }
    __syncthreads();
    int nval = E - e0;
    if (nval > EPB) nval = EPB;
    for (int p = tid; p < nval; p += 512) {
        int k = bk[p];
        rbuf[gb[k] + (p - lbase[k])] = rec[p];
    }
}

// ---------------------------------------------------------------------------
// 7) F: fine pass — one block per bucket: per-node CSR base, deg, dinv, ebuf.
// ---------------------------------------------------------------------------
__global__ __launch_bounds__(256) void fine_kernel(const unsigned int* __restrict__ rbuf,
                                                   const int* __restrict__ bbase,
                                                   int* __restrict__ base_g,
                                                   int* __restrict__ cnt_g,
                                                   float* __restrict__ dinv,
                                                   int* __restrict__ ebuf, int n) {
    __shared__ int cnt[256], lb[256], lf[256], sc[256];
    int tid = threadIdx.x, k = blockIdx.x;
    int seg0 = bbase[k], seg1 = bbase[k + 1];
    cnt[tid] = 0;
    lf[tid] = 0;
    __syncthreads();
    for (int j = seg0 + tid; j < seg1; j += 256)
        atomicAdd(&cnt[rbuf[j] >> 24], 1);
    __syncthreads();
    int cv = cnt[tid];
    sc[tid] = cv;
    __syncthreads();
    int val = cv;
    for (int off = 1; off < 256; off <<= 1) {
        int t = (tid >= off) ? sc[tid - off] : 0;
        __syncthreads();
        val += t;
        sc[tid] = val;
        __syncthreads();
    }
    lb[tid] = val - cv;   // exclusive
    __syncthreads();
    int node = k * 256 + tid;
    if (node < n) {
        base_g[node] = seg0 + lb[tid];
        cnt_g[node] = cv;
        dinv[node] = rsqrtf((float)cv + 1.f);
    }
    for (int j = seg0 + tid; j < seg1; j += 256) {
        unsigned int r = rbuf[j];
        int dl = r >> 24;
        int p = seg0 + lb[dl] + atomicAdd(&lf[dl], 1);
        ebuf[p] = (int)(r & 0xFFFFFFu);
    }
}

// ---------------------------------------------------------------------------
// 8) MFMA GEMM v4: swapped-operand, 2 row-chains x 64 cols per wave,
//    A-stream prefetch DISTANCE 2 (8 loads in flight), B hoisted to top
//    of iteration. Block(256) = 64 rows x 128 cols, grid 1563.
// ---------------------------------------------------------------------------
__global__ __launch_bounds__(256) void gemm_mfma_kernel(const float* __restrict__ x,
                                                        const __bf16* __restrict__ WT,
                                                        const float* __restrict__ dinv,
                                                        __bf16* __restrict__ xwb, int nn) {
    int tid  = threadIdx.x;
    int lane = tid & 63;
    int w    = tid >> 6;                 // wave 0..3
    int rfrag = lane & 15;
    int kg    = lane >> 4;               // 0..3
    int row0 = blockIdx.x * 64 + (w & 1) * 32;
    int col0 = (w >> 1) * 64;            // 0 or 64
    int r0 = row0 + rfrag;
    int r1 = r0 + 16;
    int lr0 = (r0 < nn) ? r0 : nn - 1;
    int lr1 = (r1 < nn) ? r1 : nn - 1;

    const float4* xr0 = (const float4*)(x + (size_t)lr0 * NFEAT);
    const float4* xr1 = (const float4*)(x + (size_t)lr1 * NFEAT);
    const __bf16* wb  = WT + (size_t)(col0 + rfrag) * NFEAT + kg * 8;

    f32x4 acc0[4] = {};
    f32x4 acc1[4] = {};

    // A staging: [slot][half], slot = ks&1, prefetched at distance 2
    float4 A0[2][2], A1[2][2];

    // prologue: stage A for ks=0,1
    {
        int i0 = kg * 2;
        A0[0][0] = xr0[i0];     A0[0][1] = xr0[i0 + 1];
        A1[0][0] = xr1[i0];     A1[0][1] = xr1[i0 + 1];
        A0[1][0] = xr0[i0 + 8]; A0[1][1] = xr0[i0 + 9];
        A1[1][0] = xr1[i0 + 8]; A1[1][1] = xr1[i0 + 9];
    }

#pragma unroll
    for (int ks = 0; ks < 8; ++ks) {
        const int cur = ks & 1;

        // 1) issue B loads for this ks (L2-resident WT; covered by cvt+A-issue)
        bf16x8 Bf[4];
#pragma unroll
        for (int nt = 0; nt < 4; ++nt) {
            Bf[nt] = *(const bf16x8*)(wb + (size_t)nt * 16 * NFEAT + ks * 32);
        }

        // 2) convert A[cur] -> fragments (frees the slot)
        float4 a0 = A0[cur][0], b0 = A0[cur][1];
        float4 a1 = A1[cur][0], b1 = A1[cur][1];
        bf16x8 af0, af1;
        af0[0] = (__bf16)a0.x; af0[1] = (__bf16)a0.y;
        af0[2] = (__bf16)a0.z; af0[3] = (__bf16)a0.w;
        af0[4] = (__bf16)b0.x; af0[5] = (__bf16)b0.y;
        af0[6] = (__bf16)b0.z; af0[7] = (__bf16)b0.w;
        af1[0] = (__bf16)a1.x; af1[1] = (__bf16)a1.y;
        af1[2] = (__bf16)a1.z; af1[3] = (__bf16)a1.w;
        af1[4] = (__bf16)b1.x; af1[5] = (__bf16)b1.y;
        af1[6] = (__bf16)b1.z; af1[7] = (__bf16)b1.w;

        // 3) issue A loads for ks+2 into the freed slot (distance-2 prefetch)
        if (ks < 6) {
            int ni = (ks + 2) * 8 + kg * 2;
            A0[cur][0] = xr0[ni]; A0[cur][1] = xr0[ni + 1];
            A1[cur][0] = xr1[ni]; A1[cur][1] = xr1[ni + 1];
        }

        // 4) MFMA cluster
#pragma unroll
        for (int nt = 0; nt < 4; ++nt) {
            acc0[nt] = __builtin_amdgcn_mfma_f32_16x16x32_bf16(Bf[nt], af0, acc0[nt], 0, 0, 0);
            acc1[nt] = __builtin_amdgcn_mfma_f32_16x16x32_bf16(Bf[nt], af1, acc1[nt], 0, 0, 0);
        }
    }

    // lane owns output row r0 (acc0) / r1 (acc1); cols col0 + nt*16 + kg*4 + reg
    if (r0 < nn) {
        float d = dinv[r0];
        __bf16* orow = xwb + (size_t)r0 * NHID + col0 + kg * 4;
#pragma unroll
        for (int nt = 0; nt < 4; ++nt) {
            bf16x4 v;
            v[0] = (__bf16)(acc0[nt][0] * d);
            v[1] = (__bf16)(acc0[nt][1] * d);
            v[2] = (__bf16)(acc0[nt][2] * d);
            v[3] = (__bf16)(acc0[nt][3] * d);
            *(bf16x4*)&orow[nt * 16] = v;
        }
    }
    if (r1 < nn) {
        float d = dinv[r1];
        __bf16* orow = xwb + (size_t)r1 * NHID + col0 + kg * 4;
#pragma unroll
        for (int nt = 0; nt < 4; ++nt) {
            bf16x4 v;
            v[0] = (__bf16)(acc1[nt][0] * d);
            v[1] = (__bf16)(acc1[nt][1] * d);
            v[2] = (__bf16)(acc1[nt][2] * d);
            v[3] = (__bf16)(acc1[nt][3] * d);
            *(bf16x4*)&orow[nt * 16] = v;
        }
    }
}

// ---------------------------------------------------------------------------
// 9) Gather + finalize: HALF-WAVE per node (32 lanes x 8B = 256B row read).
// ---------------------------------------------------------------------------
__global__ __launch_bounds__(256) void gather_kernel(const uint2* __restrict__ xb2,
                                                     const int* __restrict__ base,
                                                     const int* __restrict__ cnt,
                                                     const int* __restrict__ ebuf,
                                                     const float* __restrict__ dinv,
                                                     const float* __restrict__ bias,
                                                     const float* __restrict__ pa,
                                                     float* __restrict__ out, int n) {
    int tid = threadIdx.x;
    int sub = tid & 31;                               // sublane in half-wave
    int node = (blockIdx.x * 256 + tid) >> 5;         // one node per 32 lanes
    if (node >= n) return;

    int b = base[node];
    int deg = cnt[node];

    uint2 s0 = xb2[(size_t)node * 32 + sub];
    float a0 = __uint_as_float(s0.x << 16);
    float a1 = __uint_as_float(s0.x & 0xffff0000u);
    float a2 = __uint_as_float(s0.y << 16);
    float a3 = __uint_as_float(s0.y & 0xffff0000u);

    int k = 0;
    for (; k + 4 <= deg; k += 4) {
        int r0 = ebuf[b + k + 0];
        int r1 = ebuf[b + k + 1];
        int r2 = ebuf[b + k + 2];
        int r3 = ebuf[b + k + 3];
        uint2 v0 = xb2[(size_t)r0 * 32 + sub];
        uint2 v1 = xb2[(size_t)r1 * 32 + sub];
        uint2 v2 = xb2[(size_t)r2 * 32 + sub];
        uint2 v3 = xb2[(size_t)r3 * 32 + sub];
        a0 += __uint_as_float(v0.x << 16) + __uint_as_float(v1.x << 16)
            + __uint_as_float(v2.x << 16) + __uint_as_float(v3.x << 16);
        a1 += __uint_as_float(v0.x & 0xffff0000u) + __uint_as_float(v1.x & 0xffff0000u)
            + __uint_as_float(v2.x & 0xffff0000u) + __uint_as_float(v3.x & 0xffff0000u);
        a2 += __uint_as_float(v0.y << 16) + __uint_as_float(v1.y << 16)
            + __uint_as_float(v2.y << 16) + __uint_as_float(v3.y << 16);
        a3 += __uint_as_float(v0.y & 0xffff0000u) + __uint_as_float(v1.y & 0xffff0000u)
            + __uint_as_float(v2.y & 0xffff0000u) + __uint_as_float(v3.y & 0xffff0000u);
    }
    for (; k < deg; ++k) {
        int r = ebuf[b + k];
        uint2 v = xb2[(size_t)r * 32 + sub];
        a0 += __uint_as_float(v.x << 16);
        a1 += __uint_as_float(v.x & 0xffff0000u);
        a2 += __uint_as_float(v.y << 16);
        a3 += __uint_as_float(v.y & 0xffff0000u);
    }

    float s = dinv[node];
    float alpha = pa[0];
    float4 bb = ((const float4*)bias)[sub];
    float o0 = s * a0 + bb.x;
    float o1 = s * a1 + bb.y;
    float o2 = s * a2 + bb.z;
    float o3 = s * a3 + bb.w;
    o0 = o0 > 0.f ? o0 : alpha * o0;
    o1 = o1 > 0.f ? o1 : alpha * o1;
    o2 = o2 > 0.f ? o2 : alpha * o2;
    o3 = o3 > 0.f ? o3 : alpha * o3;
    ((float4*)out)[(size_t)node * 32 + sub] = make_float4(o0, o1, o2, o3);
}

// ---------------------------------------------------------------------------
extern "C" void kernel_launch(void* const* d_in, const int* in_sizes, int n_in,
                              void* d_out, int out_size, void* d_ws, size_t ws_size,
                              hipStream_t stream) {
    const float* x    = (const float*)d_in[0];
    const int*   ei   = (const int*)d_in[1];   // int32, [2,E] row-major
    const float* W    = (const float*)d_in[2];
    const float* bias = (const float*)d_in[3];
    const float* pa   = (const float*)d_in[4];
    const float* u    = (const float*)d_in[5];

    int n = in_sizes[0] / NFEAT;     // 100000
    int e = in_sizes[1] / 2;         // 1600000
    const int* erow = ei;            // sources
    const int* ecol = ei + e;        // targets

    float* out = (float*)d_out;
    char* ws = (char*)d_ws;
    // workspace layout (bytes)
    float*        scal   = (float*)(ws);                    // 4 B
    int*          btot   = (int*)  (ws + 0x0001000);        // 392 ints
    int*          bbase  = (int*)  (ws + 0x0002000);        // 392 ints
    __bf16*       WT     = (__bf16*)(ws + 0x0010000);       // 64 KB
    int*          base_g = (int*)  (ws + 0x0100000);        // 400 KB
    int*          cnt_g  = (int*)  (ws + 0x0200000);        // 400 KB
    float*        dinv   = (float*)(ws + 0x0300000);        // 400 KB
    int*          blkhist= (int*)  (ws + 0x0400000);        // 611 KB
    unsigned int* rbuf   = (unsigned int*)(ws + 0x0500000); // 6.4 MB
    int*          ebuf   = (int*)  (ws + 0x0C00000);        // 6.4 MB
    __bf16*       xwb    = (__bf16*)(ws + 0x1300000);       // 25.6 MB

    sigma_kernel<<<1, 256, 0, stream>>>(W, u, scal);
    wt_kernel<<<(NFEAT * NHID) / 256, 256, 0, stream>>>(W, scal, WT);

    hist_kernel<<<NBLK, 256, 0, stream>>>(ecol, blkhist, e);
    scan_rows_kernel<<<(NBK + 3) / 4, 256, 0, stream>>>(blkhist, btot);
    scan_buckets_kernel<<<1, 512, 0, stream>>>(btot, bbase);
    coarse_scatter_kernel<<<NBLK, 512, 0, stream>>>(erow, ecol, blkhist, bbase, rbuf, e);
    fine_kernel<<<NBK, 256, 0, stream>>>(rbuf, bbase, base_g, cnt_g, dinv, ebuf, n);

    gemm_mfma_kernel<<<(n + 63) / 64, 256, 0, stream>>>(x, WT, dinv, xwb, n);

    long long gunits = (long long)n * 32;
    gather_kernel<<<(int)((gunits + 255) / 256), 256, 0, stream>>>(
        (const uint2*)xwb, base_g, cnt_g, ebuf, dinv, bias, pa, out, n);
}

// Round 8
// 161.104 us; speedup vs baseline: 1.0979x; 1.0979x over previous
//
#include <hip/hip_runtime.h>

#define NFEAT 256
#define NHID  128

#define NBK   391     // node buckets of 256 nodes (ceil(100000/256))
#define EPB   4096    // edges per block in hist/scatter passes
#define NBLK  391     // edge blocks (ceil(1600000/4096))

typedef __bf16 bf16x8 __attribute__((ext_vector_type(8)));
typedef __bf16 bf16x4 __attribute__((ext_vector_type(4)));
typedef float  f32x4  __attribute__((ext_vector_type(4)));

// ---------------------------------------------------------------------------
// 1) Spectral norm: one power iteration -> scal[0] = 1/sigma
// ---------------------------------------------------------------------------
__global__ __launch_bounds__(256) void sigma_kernel(const float* __restrict__ W,
                                                    const float* __restrict__ u,
                                                    float* __restrict__ scal) {
    __shared__ float v[NHID];
    __shared__ float red[256];
    int tid = threadIdx.x;

    float t = 0.f;
    if (tid < NHID) {
        for (int i = 0; i < NFEAT; ++i) t += W[i * NHID + tid] * u[i];
    }
    red[tid] = (tid < NHID) ? t * t : 0.f;
    __syncthreads();
    for (int s = 128; s > 0; s >>= 1) {
        if (tid < s) red[tid] += red[tid + s];
        __syncthreads();
    }
    float nv = sqrtf(red[0]);
    float inv_nv = 1.f / (nv + 1e-12f);
    __syncthreads();
    if (tid < NHID) v[tid] = t * inv_nv;
    __syncthreads();

    float wv = 0.f;
    for (int j = 0; j < NHID; ++j) wv += W[tid * NHID + j] * v[j];
    red[tid] = wv * wv;
    __syncthreads();
    for (int s = 128; s > 0; s >>= 1) {
        if (tid < s) red[tid] += red[tid + s];
        __syncthreads();
    }
    if (tid == 0) {
        float n2  = red[0];
        float nwv = sqrtf(n2);
        float sigma = n2 / (nwv + 1e-12f);
        scal[0] = 1.f / sigma;
    }
}

// ---------------------------------------------------------------------------
// 2) W^T in bf16, scaled by 1/sigma
// ---------------------------------------------------------------------------
__global__ __launch_bounds__(256) void wt_kernel(const float* __restrict__ W,
                                                 const float* __restrict__ scal,
                                                 __bf16* __restrict__ WT) {
    int idx = blockIdx.x * 256 + threadIdx.x;
    int c = idx >> 8;
    int r = idx & 255;
    WT[c * NFEAT + r] = (__bf16)(W[r * NHID + c] * scal[0]);
}

// ---------------------------------------------------------------------------
// 3) C1: per-block histogram over coarse buckets (bucket = dst >> 8)
// ---------------------------------------------------------------------------
__global__ __launch_bounds__(256) void hist_kernel(const int* __restrict__ ecol,
                                                   int* __restrict__ blkhist, int E) {
    __shared__ int hist[NBK];
    int tid = threadIdx.x, b = blockIdx.x;
    for (int k = tid; k < NBK; k += 256) hist[k] = 0;
    __syncthreads();
    int e0 = b * EPB;
#pragma unroll
    for (int j = 0; j < 16; ++j) {
        int idx = e0 + j * 256 + tid;
        if (idx < E) atomicAdd(&hist[ecol[idx] >> 8], 1);
    }
    __syncthreads();
    for (int k = tid; k < NBK; k += 256) blkhist[k * NBLK + b] = hist[k];
}

// ---------------------------------------------------------------------------
// 4) C3a: exclusive scan of each blkhist row (one wave per bucket) + row total
// ---------------------------------------------------------------------------
__global__ __launch_bounds__(256) void scan_rows_kernel(int* __restrict__ blkhist,
                                                        int* __restrict__ btot) {
    int k = blockIdx.x * 4 + (threadIdx.x >> 6);
    int lane = threadIdx.x & 63;
    if (k >= NBK) return;
    int carry = 0;
    for (int c0 = 0; c0 < NBLK; c0 += 64) {
        int b = c0 + lane;
        int v = (b < NBLK) ? blkhist[k * NBLK + b] : 0;
        int orig = v;
#pragma unroll
        for (int d = 1; d < 64; d <<= 1) {
            int t = __shfl_up(v, (unsigned)d, 64);
            if (lane >= d) v += t;
        }
        if (b < NBLK) blkhist[k * NBLK + b] = carry + v - orig;   // exclusive
        carry += __shfl(v, 63, 64);
    }
    if (lane == 0) btot[k] = carry;
}

// ---------------------------------------------------------------------------
// 5) C3b: exclusive scan of bucket totals -> bucket_base[0..NBK]
// ---------------------------------------------------------------------------
__global__ __launch_bounds__(512) void scan_buckets_kernel(const int* __restrict__ btot,
                                                           int* __restrict__ bbase) {
    __shared__ int s[512];
    int tid = threadIdx.x;
    int v = (tid < NBK) ? btot[tid] : 0;
    s[tid] = v;
    __syncthreads();
    int val = v;
    for (int off = 1; off < 512; off <<= 1) {
        int t = (tid >= off) ? s[tid - off] : 0;
        __syncthreads();
        val += t;
        s[tid] = val;
        __syncthreads();
    }
    if (tid <= NBK) bbase[tid] = val - v;   // tid==NBK (v=0) -> total
}

// ---------------------------------------------------------------------------
// 6) C4: coarse scatter — LDS-reorder 4096 edges by bucket, write segments
// ---------------------------------------------------------------------------
__global__ __launch_bounds__(512) void coarse_scatter_kernel(const int* __restrict__ erow,
                                                             const int* __restrict__ ecol,
                                                             const int* __restrict__ blkhist,
                                                             const int* __restrict__ bbase,
                                                             unsigned int* __restrict__ rbuf,
                                                             int E) {
    __shared__ unsigned int rec[EPB];
    __shared__ unsigned short bk[EPB];
    __shared__ int hist[NBK], sc[512], lbase[NBK], lfill[NBK], gb[NBK];
    int tid = threadIdx.x, b = blockIdx.x;
    for (int k = tid; k < NBK; k += 512) { hist[k] = 0; lfill[k] = 0; }
    __syncthreads();
    int e0 = b * EPB;
    unsigned int rv[8];
    int kv[8];
#pragma unroll
    for (int j = 0; j < 8; ++j) {
        int idx = e0 + j * 512 + tid;
        if (idx < E) {
            int c = ecol[idx];
            int s = erow[idx];
            int k = c >> 8;
            kv[j] = k;
            rv[j] = ((unsigned int)(c & 255) << 24) | (unsigned int)s;
            atomicAdd(&hist[k], 1);
        } else kv[j] = -1;
    }
    __syncthreads();
    int hv = (tid < NBK) ? hist[tid] : 0;
    sc[tid] = hv;
    __syncthreads();
    int val = hv;
    for (int off = 1; off < 512; off <<= 1) {
        int t = (tid >= off) ? sc[tid - off] : 0;
        __syncthreads();
        val += t;
        sc[tid] = val;
        __syncthreads();
    }
    if (tid < NBK) {
        lbase[tid] = val - hv;
        gb[tid] = bbase[tid] + blkhist[tid * NBLK + b];
    }
    __syncthreads();
#pragma unroll
    for (int j = 0; j < 8; ++j) {
        if (kv[j] >= 0) {
            int p = lbase[kv[j]] + atomicAdd(&lfill[kv[j]], 1);
            rec[p] = rv[j];
            bk[p] = (unsigned short)kv[j];
        }
    }
    __syncthreads();
    int nval = E - e0;
    if (nval > EPB) nval = EPB;
    for (int p = tid; p < nval; p += 512) {
        int k = bk[p];
        rbuf[gb[k] + (p - lbase[k])] = rec[p];
    }
}

// ---------------------------------------------------------------------------
// 7) F: fine pass — one block per bucket: per-node CSR base, deg, dinv, ebuf.
// ---------------------------------------------------------------------------
__global__ __launch_bounds__(256) void fine_kernel(const unsigned int* __restrict__ rbuf,
                                                   const int* __restrict__ bbase,
                                                   int* __restrict__ base_g,
                                                   int* __restrict__ cnt_g,
                                                   float* __restrict__ dinv,
                                                   int* __restrict__ ebuf, int n) {
    __shared__ int cnt[256], lb[256], lf[256], sc[256];
    int tid = threadIdx.x, k = blockIdx.x;
    int seg0 = bbase[k], seg1 = bbase[k + 1];
    cnt[tid] = 0;
    lf[tid] = 0;
    __syncthreads();
    for (int j = seg0 + tid; j < seg1; j += 256)
        atomicAdd(&cnt[rbuf[j] >> 24], 1);
    __syncthreads();
    int cv = cnt[tid];
    sc[tid] = cv;
    __syncthreads();
    int val = cv;
    for (int off = 1; off < 256; off <<= 1) {
        int t = (tid >= off) ? sc[tid - off] : 0;
        __syncthreads();
        val += t;
        sc[tid] = val;
        __syncthreads();
    }
    lb[tid] = val - cv;   // exclusive
    __syncthreads();
    int node = k * 256 + tid;
    if (node < n) {
        base_g[node] = seg0 + lb[tid];
        cnt_g[node] = cv;
        dinv[node] = rsqrtf((float)cv + 1.f);
    }
    for (int j = seg0 + tid; j < seg1; j += 256) {
        unsigned int r = rbuf[j];
        int dl = r >> 24;
        int p = seg0 + lb[dl] + atomicAdd(&lf[dl], 1);
        ebuf[p] = (int)(r & 0xFFFFFFu);
    }
}

// ---------------------------------------------------------------------------
// 8) MFMA GEMM v5: LDS-staged bf16 x-tile, double-buffered, XOR-swizzled.
//    Block = 256 thr / 4 waves / 64 rows; K = 4 chunks of 64.
//    Staging: each thread cvt's 16 fp32 -> 16 bf16, 2 ds_write_b128 (swz).
//    Compute: proven swapped-operand geometry, A via 1 ds_read_b128/chain.
//    Swizzle: 16B slot s at row r lives at physical slot s ^ (r&7).
// ---------------------------------------------------------------------------
__global__ __launch_bounds__(256) void gemm_mfma_kernel(const float* __restrict__ x,
                                                        const __bf16* __restrict__ WT,
                                                        const float* __restrict__ dinv,
                                                        __bf16* __restrict__ xwb, int nn) {
    __shared__ __bf16 xs[2][64][64];   // 2 x 8KB

    int tid  = threadIdx.x;
    int lane = tid & 63;
    int w    = tid >> 6;                 // wave 0..3
    int rfrag = lane & 15;
    int kg    = lane >> 4;               // 0..3
    int row0 = blockIdx.x * 64;

    // ---- staging coords: thread t -> row t/4, 16-float segment t%4
    int srow = tid >> 2;                 // 0..63
    int sseg = tid & 3;                  // 0..3 (16 floats = 2 x 16B-bf16 slots)
    int gsrow = row0 + srow;
    if (gsrow >= nn) gsrow = nn - 1;
    const float4* sx = (const float4*)(x + (size_t)gsrow * NFEAT) + sseg * 4;
    int sslot = sseg * 2;                // logical 16B slot (0,2,4,6)
    int sr7 = srow & 7;

    // ---- compute coords (identical to proven R5/R7 geometry)
    int crow0 = (w & 1) * 32 + rfrag;    // chain0 row in tile
    int col0 = (w >> 1) * 64;            // 0 or 64
    int r0 = row0 + crow0;
    int r1 = r0 + 16;
    const __bf16* wb = WT + (size_t)(col0 + rfrag) * NFEAT + kg * 8;
    int cr7 = crow0 & 7;                 // same for crow0+16 (16 % 8 == 0)

    f32x4 acc0[4] = {};
    f32x4 acc1[4] = {};

    // ---- prologue: stage chunk 0 into buffer 0
    {
        float4 f0 = sx[0], f1 = sx[1], f2 = sx[2], f3 = sx[3];
        bf16x8 h0, h1;
        h0[0] = (__bf16)f0.x; h0[1] = (__bf16)f0.y; h0[2] = (__bf16)f0.z; h0[3] = (__bf16)f0.w;
        h0[4] = (__bf16)f1.x; h0[5] = (__bf16)f1.y; h0[6] = (__bf16)f1.z; h0[7] = (__bf16)f1.w;
        h1[0] = (__bf16)f2.x; h1[1] = (__bf16)f2.y; h1[2] = (__bf16)f2.z; h1[3] = (__bf16)f2.w;
        h1[4] = (__bf16)f3.x; h1[5] = (__bf16)f3.y; h1[6] = (__bf16)f3.z; h1[7] = (__bf16)f3.w;
        *(bf16x8*)&xs[0][srow][(sslot ^ sr7) * 8]       = h0;
        *(bf16x8*)&xs[0][srow][((sslot + 1) ^ sr7) * 8] = h1;
    }
    __syncthreads();

#pragma unroll
    for (int c = 0; c < 4; ++c) {
        const int cur = c & 1;

        // 1) issue next chunk's global loads (no deps -> can fly under MFMA)
        float4 f0, f1, f2, f3;
        if (c < 3) {
            const float4* p = sx + (c + 1) * 16;
            f0 = p[0]; f1 = p[1]; f2 = p[2]; f3 = p[3];
        }

        // 2) compute on xs[cur]
#pragma unroll
        for (int ks = 0; ks < 2; ++ks) {
            int slog = ks * 4 + kg;                       // logical 16B slot
            bf16x8 af0 = *(const bf16x8*)&xs[cur][crow0][(slog ^ cr7) * 8];
            bf16x8 af1 = *(const bf16x8*)&xs[cur][crow0 + 16][(slog ^ cr7) * 8];
            int koff = c * 64 + ks * 32;
#pragma unroll
            for (int nt = 0; nt < 4; ++nt) {
                bf16x8 bf = *(const bf16x8*)(wb + (size_t)nt * 16 * NFEAT + koff);
                acc0[nt] = __builtin_amdgcn_mfma_f32_16x16x32_bf16(bf, af0, acc0[nt], 0, 0, 0);
                acc1[nt] = __builtin_amdgcn_mfma_f32_16x16x32_bf16(bf, af1, acc1[nt], 0, 0, 0);
            }
        }

        // 3) cvt + swizzled ds_write of next chunk into the other buffer
        if (c < 3) {
            bf16x8 h0, h1;
            h0[0] = (__bf16)f0.x; h0[1] = (__bf16)f0.y; h0[2] = (__bf16)f0.z; h0[3] = (__bf16)f0.w;
            h0[4] = (__bf16)f1.x; h0[5] = (__bf16)f1.y; h0[6] = (__bf16)f1.z; h0[7] = (__bf16)f1.w;
            h1[0] = (__bf16)f2.x; h1[1] = (__bf16)f2.y; h1[2] = (__bf16)f2.z; h1[3] = (__bf16)f2.w;
            h1[4] = (__bf16)f3.x; h1[5] = (__bf16)f3.y; h1[6] = (__bf16)f3.z; h1[7] = (__bf16)f3.w;
            *(bf16x8*)&xs[cur ^ 1][srow][(sslot ^ sr7) * 8]       = h0;
            *(bf16x8*)&xs[cur ^ 1][srow][((sslot + 1) ^ sr7) * 8] = h1;
        }
        __syncthreads();
    }

    // ---- epilogue: lane owns rows r0/r1, cols col0 + nt*16 + kg*4 + reg
    if (r0 < nn) {
        float d = dinv[r0];
        __bf16* orow = xwb + (size_t)r0 * NHID + col0 + kg * 4;
#pragma unroll
        for (int nt = 0; nt < 4; ++nt) {
            bf16x4 v;
            v[0] = (__bf16)(acc0[nt][0] * d);
            v[1] = (__bf16)(acc0[nt][1] * d);
            v[2] = (__bf16)(acc0[nt][2] * d);
            v[3] = (__bf16)(acc0[nt][3] * d);
            *(bf16x4*)&orow[nt * 16] = v;
        }
    }
    if (r1 < nn) {
        float d = dinv[r1];
        __bf16* orow = xwb + (size_t)r1 * NHID + col0 + kg * 4;
#pragma unroll
        for (int nt = 0; nt < 4; ++nt) {
            bf16x4 v;
            v[0] = (__bf16)(acc1[nt][0] * d);
            v[1] = (__bf16)(acc1[nt][1] * d);
            v[2] = (__bf16)(acc1[nt][2] * d);
            v[3] = (__bf16)(acc1[nt][3] * d);
            *(bf16x4*)&orow[nt * 16] = v;
        }
    }
}

// ---------------------------------------------------------------------------
// 9) Gather + finalize: HALF-WAVE per node (32 lanes x 8B = 256B row read).
// ---------------------------------------------------------------------------
__global__ __launch_bounds__(256) void gather_kernel(const uint2* __restrict__ xb2,
                                                     const int* __restrict__ base,
                                                     const int* __restrict__ cnt,
                                                     const int* __restrict__ ebuf,
                                                     const float* __restrict__ dinv,
                                                     const float* __restrict__ bias,
                                                     const float* __restrict__ pa,
                                                     float* __restrict__ out, int n) {
    int tid = threadIdx.x;
    int sub = tid & 31;                               // sublane in half-wave
    int node = (blockIdx.x * 256 + tid) >> 5;         // one node per 32 lanes
    if (node >= n) return;

    int b = base[node];
    int deg = cnt[node];

    uint2 s0 = xb2[(size_t)node * 32 + sub];
    float a0 = __uint_as_float(s0.x << 16);
    float a1 = __uint_as_float(s0.x & 0xffff0000u);
    float a2 = __uint_as_float(s0.y << 16);
    float a3 = __uint_as_float(s0.y & 0xffff0000u);

    int k = 0;
    for (; k + 4 <= deg; k += 4) {
        int r0 = ebuf[b + k + 0];
        int r1 = ebuf[b + k + 1];
        int r2 = ebuf[b + k + 2];
        int r3 = ebuf[b + k + 3];
        uint2 v0 = xb2[(size_t)r0 * 32 + sub];
        uint2 v1 = xb2[(size_t)r1 * 32 + sub];
        uint2 v2 = xb2[(size_t)r2 * 32 + sub];
        uint2 v3 = xb2[(size_t)r3 * 32 + sub];
        a0 += __uint_as_float(v0.x << 16) + __uint_as_float(v1.x << 16)
            + __uint_as_float(v2.x << 16) + __uint_as_float(v3.x << 16);
        a1 += __uint_as_float(v0.x & 0xffff0000u) + __uint_as_float(v1.x & 0xffff0000u)
            + __uint_as_float(v2.x & 0xffff0000u) + __uint_as_float(v3.x & 0xffff0000u);
        a2 += __uint_as_float(v0.y << 16) + __uint_as_float(v1.y << 16)
            + __uint_as_float(v2.y << 16) + __uint_as_float(v3.y << 16);
        a3 += __uint_as_float(v0.y & 0xffff0000u) + __uint_as_float(v1.y & 0xffff0000u)
            + __uint_as_float(v2.y & 0xffff0000u) + __uint_as_float(v3.y & 0xffff0000u);
    }
    for (; k < deg; ++k) {
        int r = ebuf[b + k];
        uint2 v = xb2[(size_t)r * 32 + sub];
        a0 += __uint_as_float(v.x << 16);
        a1 += __uint_as_float(v.x & 0xffff0000u);
        a2 += __uint_as_float(v.y << 16);
        a3 += __uint_as_float(v.y & 0xffff0000u);
    }

    float s = dinv[node];
    float alpha = pa[0];
    float4 bb = ((const float4*)bias)[sub];
    float o0 = s * a0 + bb.x;
    float o1 = s * a1 + bb.y;
    float o2 = s * a2 + bb.z;
    float o3 = s * a3 + bb.w;
    o0 = o0 > 0.f ? o0 : alpha * o0;
    o1 = o1 > 0.f ? o1 : alpha * o1;
    o2 = o2 > 0.f ? o2 : alpha * o2;
    o3 = o3 > 0.f ? o3 : alpha * o3;
    ((float4*)out)[(size_t)node * 32 + sub] = make_float4(o0, o1, o2, o3);
}

// ---------------------------------------------------------------------------
extern "C" void kernel_launch(void* const* d_in, const int* in_sizes, int n_in,
                              void* d_out, int out_size, void* d_ws, size_t ws_size,
                              hipStream_t stream) {
    const float* x    = (const float*)d_in[0];
    const int*   ei   = (const int*)d_in[1];   // int32, [2,E] row-major
    const float* W    = (const float*)d_in[2];
    const float* bias = (const float*)d_in[3];
    const float* pa   = (const float*)d_in[4];
    const float* u    = (const float*)d_in[5];

    int n = in_sizes[0] / NFEAT;     // 100000
    int e = in_sizes[1] / 2;         // 1600000
    const int* erow = ei;            // sources
    const int* ecol = ei + e;        // targets

    float* out = (float*)d_out;
    char* ws = (char*)d_ws;
    // workspace layout (bytes)
    float*        scal   = (float*)(ws);                    // 4 B
    int*          btot   = (int*)  (ws + 0x0001000);        // 392 ints
    int*          bbase  = (int*)  (ws + 0x0002000);        // 392 ints
    __bf16*       WT     = (__bf16*)(ws + 0x0010000);       // 64 KB
    int*          base_g = (int*)  (ws + 0x0100000);        // 400 KB
    int*          cnt_g  = (int*)  (ws + 0x0200000);        // 400 KB
    float*        dinv   = (float*)(ws + 0x0300000);        // 400 KB
    int*          blkhist= (int*)  (ws + 0x0400000);        // 611 KB
    unsigned int* rbuf   = (unsigned int*)(ws + 0x0500000); // 6.4 MB
    int*          ebuf   = (int*)  (ws + 0x0C00000);        // 6.4 MB
    __bf16*       xwb    = (__bf16*)(ws + 0x1300000);       // 25.6 MB

    sigma_kernel<<<1, 256, 0, stream>>>(W, u, scal);
    wt_kernel<<<(NFEAT * NHID) / 256, 256, 0, stream>>>(W, scal, WT);

    hist_kernel<<<NBLK, 256, 0, stream>>>(ecol, blkhist, e);
    scan_rows_kernel<<<(NBK + 3) / 4, 256, 0, stream>>>(blkhist, btot);
    scan_buckets_kernel<<<1, 512, 0, stream>>>(btot, bbase);
    coarse_scatter_kernel<<<NBLK, 512, 0, stream>>>(erow, ecol, blkhist, bbase, rbuf, e);
    fine_kernel<<<NBK, 256, 0, stream>>>(rbuf, bbase, base_g, cnt_g, dinv, ebuf, n);

    gemm_mfma_kernel<<<(n + 63) / 64, 256, 0, stream>>>(x, WT, dinv, xwb, n);

    long long gunits = (long long)n * 32;
    gather_kernel<<<(int)((gunits + 255) / 256), 256, 0, stream>>>(
        (const uint2*)xwb, base_g, cnt_g, ebuf, dinv, bias, pa, out, n);
}

// Round 9
// 159.202 us; speedup vs baseline: 1.1110x; 1.0119x over previous
//
#include <hip/hip_runtime.h>

#define NFEAT 256
#define NHID  128

#define NBK   391     // node buckets of 256 nodes (ceil(100000/256))
#define EPB   4096    // edges per block in hist/scatter passes
#define NBLK  391     // edge blocks (ceil(1600000/4096))

typedef __bf16 bf16x8 __attribute__((ext_vector_type(8)));
typedef __bf16 bf16x4 __attribute__((ext_vector_type(4)));
typedef float  f32x4  __attribute__((ext_vector_type(4)));

// ---------------------------------------------------------------------------
// 1) Spectral norm: one power iteration -> scal[0] = 1/sigma
// ---------------------------------------------------------------------------
__global__ __launch_bounds__(256) void sigma_kernel(const float* __restrict__ W,
                                                    const float* __restrict__ u,
                                                    float* __restrict__ scal) {
    __shared__ float v[NHID];
    __shared__ float red[256];
    int tid = threadIdx.x;

    float t = 0.f;
    if (tid < NHID) {
        for (int i = 0; i < NFEAT; ++i) t += W[i * NHID + tid] * u[i];
    }
    red[tid] = (tid < NHID) ? t * t : 0.f;
    __syncthreads();
    for (int s = 128; s > 0; s >>= 1) {
        if (tid < s) red[tid] += red[tid + s];
        __syncthreads();
    }
    float nv = sqrtf(red[0]);
    float inv_nv = 1.f / (nv + 1e-12f);
    __syncthreads();
    if (tid < NHID) v[tid] = t * inv_nv;
    __syncthreads();

    float wv = 0.f;
    for (int j = 0; j < NHID; ++j) wv += W[tid * NHID + j] * v[j];
    red[tid] = wv * wv;
    __syncthreads();
    for (int s = 128; s > 0; s >>= 1) {
        if (tid < s) red[tid] += red[tid + s];
        __syncthreads();
    }
    if (tid == 0) {
        float n2  = red[0];
        float nwv = sqrtf(n2);
        float sigma = n2 / (nwv + 1e-12f);
        scal[0] = 1.f / sigma;
    }
}

// ---------------------------------------------------------------------------
// 2) W^T in bf16, scaled by 1/sigma
// ---------------------------------------------------------------------------
__global__ __launch_bounds__(256) void wt_kernel(const float* __restrict__ W,
                                                 const float* __restrict__ scal,
                                                 __bf16* __restrict__ WT) {
    int idx = blockIdx.x * 256 + threadIdx.x;
    int c = idx >> 8;
    int r = idx & 255;
    WT[c * NFEAT + r] = (__bf16)(W[r * NHID + c] * scal[0]);
}

// ---------------------------------------------------------------------------
// 3) C1: per-block histogram over coarse buckets (bucket = dst >> 8)
// ---------------------------------------------------------------------------
__global__ __launch_bounds__(256) void hist_kernel(const int* __restrict__ ecol,
                                                   int* __restrict__ blkhist, int E) {
    __shared__ int hist[NBK];
    int tid = threadIdx.x, b = blockIdx.x;
    for (int k = tid; k < NBK; k += 256) hist[k] = 0;
    __syncthreads();
    int e0 = b * EPB;
#pragma unroll
    for (int j = 0; j < 16; ++j) {
        int idx = e0 + j * 256 + tid;
        if (idx < E) atomicAdd(&hist[ecol[idx] >> 8], 1);
    }
    __syncthreads();
    for (int k = tid; k < NBK; k += 256) blkhist[k * NBLK + b] = hist[k];
}

// ---------------------------------------------------------------------------
// 4) C3a: exclusive scan of each blkhist row (one wave per bucket) + row total
// ---------------------------------------------------------------------------
__global__ __launch_bounds__(256) void scan_rows_kernel(int* __restrict__ blkhist,
                                                        int* __restrict__ btot) {
    int k = blockIdx.x * 4 + (threadIdx.x >> 6);
    int lane = threadIdx.x & 63;
    if (k >= NBK) return;
    int carry = 0;
    for (int c0 = 0; c0 < NBLK; c0 += 64) {
        int b = c0 + lane;
        int v = (b < NBLK) ? blkhist[k * NBLK + b] : 0;
        int orig = v;
#pragma unroll
        for (int d = 1; d < 64; d <<= 1) {
            int t = __shfl_up(v, (unsigned)d, 64);
            if (lane >= d) v += t;
        }
        if (b < NBLK) blkhist[k * NBLK + b] = carry + v - orig;   // exclusive
        carry += __shfl(v, 63, 64);
    }
    if (lane == 0) btot[k] = carry;
}

// ---------------------------------------------------------------------------
// 5) C3b: exclusive scan of bucket totals -> bucket_base[0..NBK]
// ---------------------------------------------------------------------------
__global__ __launch_bounds__(512) void scan_buckets_kernel(const int* __restrict__ btot,
                                                           int* __restrict__ bbase) {
    __shared__ int s[512];
    int tid = threadIdx.x;
    int v = (tid < NBK) ? btot[tid] : 0;
    s[tid] = v;
    __syncthreads();
    int val = v;
    for (int off = 1; off < 512; off <<= 1) {
        int t = (tid >= off) ? s[tid - off] : 0;
        __syncthreads();
        val += t;
        s[tid] = val;
        __syncthreads();
    }
    if (tid <= NBK) bbase[tid] = val - v;   // tid==NBK (v=0) -> total
}

// ---------------------------------------------------------------------------
// 6) C4: coarse scatter — LDS-reorder 4096 edges by bucket, write segments
// ---------------------------------------------------------------------------
__global__ __launch_bounds__(512) void coarse_scatter_kernel(const int* __restrict__ erow,
                                                             const int* __restrict__ ecol,
                                                             const int* __restrict__ blkhist,
                                                             const int* __restrict__ bbase,
                                                             unsigned int* __restrict__ rbuf,
                                                             int E) {
    __shared__ unsigned int rec[EPB];
    __shared__ unsigned short bk[EPB];
    __shared__ int hist[NBK], sc[512], lbase[NBK], lfill[NBK], gb[NBK];
    int tid = threadIdx.x, b = blockIdx.x;
    for (int k = tid; k < NBK; k += 512) { hist[k] = 0; lfill[k] = 0; }
    __syncthreads();
    int e0 = b * EPB;
    unsigned int rv[8];
    int kv[8];
#pragma unroll
    for (int j = 0; j < 8; ++j) {
        int idx = e0 + j * 512 + tid;
        if (idx < E) {
            int c = ecol[idx];
            int s = erow[idx];
            int k = c >> 8;
            kv[j] = k;
            rv[j] = ((unsigned int)(c & 255) << 24) | (unsigned int)s;
            atomicAdd(&hist[k], 1);
        } else kv[j] = -1;
    }
    __syncthreads();
    int hv = (tid < NBK) ? hist[tid] : 0;
    sc[tid] = hv;
    __syncthreads();
    int val = hv;
    for (int off = 1; off < 512; off <<= 1) {
        int t = (tid >= off) ? sc[tid - off] : 0;
        __syncthreads();
        val += t;
        sc[tid] = val;
        __syncthreads();
    }
    if (tid < NBK) {
        lbase[tid] = val - hv;
        gb[tid] = bbase[tid] + blkhist[tid * NBLK + b];
    }
    __syncthreads();
#pragma unroll
    for (int j = 0; j < 8; ++j) {
        if (kv[j] >= 0) {
            int p = lbase[kv[j]] + atomicAdd(&lfill[kv[j]], 1);
            rec[p] = rv[j];
            bk[p] = (unsigned short)kv[j];
        }
    }
    __syncthreads();
    int nval = E - e0;
    if (nval > EPB) nval = EPB;
    for (int p = tid; p < nval; p += 512) {
        int k = bk[p];
        rbuf[gb[k] + (p - lbase[k])] = rec[p];
    }
}

// ---------------------------------------------------------------------------
// 7) F: fine pass — one block per bucket: per-node CSR base, deg, dinv, ebuf.
// ---------------------------------------------------------------------------
__global__ __launch_bounds__(256) void fine_kernel(const unsigned int* __restrict__ rbuf,
                                                   const int* __restrict__ bbase,
                                                   int* __restrict__ base_g,
                                                   int* __restrict__ cnt_g,
                                                   float* __restrict__ dinv,
                                                   int* __restrict__ ebuf, int n) {
    __shared__ int cnt[256], lb[256], lf[256], sc[256];
    int tid = threadIdx.x, k = blockIdx.x;
    int seg0 = bbase[k], seg1 = bbase[k + 1];
    cnt[tid] = 0;
    lf[tid] = 0;
    __syncthreads();
    for (int j = seg0 + tid; j < seg1; j += 256)
        atomicAdd(&cnt[rbuf[j] >> 24], 1);
    __syncthreads();
    int cv = cnt[tid];
    sc[tid] = cv;
    __syncthreads();
    int val = cv;
    for (int off = 1; off < 256; off <<= 1) {
        int t = (tid >= off) ? sc[tid - off] : 0;
        __syncthreads();
        val += t;
        sc[tid] = val;
        __syncthreads();
    }
    lb[tid] = val - cv;   // exclusive
    __syncthreads();
    int node = k * 256 + tid;
    if (node < n) {
        base_g[node] = seg0 + lb[tid];
        cnt_g[node] = cv;
        dinv[node] = rsqrtf((float)cv + 1.f);
    }
    for (int j = seg0 + tid; j < seg1; j += 256) {
        unsigned int r = rbuf[j];
        int dl = r >> 24;
        int p = seg0 + lb[dl] + atomicAdd(&lf[dl], 1);
        ebuf[p] = (int)(r & 0xFFFFFFu);
    }
}

// ---------------------------------------------------------------------------
// 8) MFMA GEMM v5: LDS-staged bf16 x-tile, double-buffered, XOR-swizzled.
// ---------------------------------------------------------------------------
__global__ __launch_bounds__(256) void gemm_mfma_kernel(const float* __restrict__ x,
                                                        const __bf16* __restrict__ WT,
                                                        const float* __restrict__ dinv,
                                                        __bf16* __restrict__ xwb, int nn) {
    __shared__ __bf16 xs[2][64][64];   // 2 x 8KB

    int tid  = threadIdx.x;
    int lane = tid & 63;
    int w    = tid >> 6;                 // wave 0..3
    int rfrag = lane & 15;
    int kg    = lane >> 4;               // 0..3
    int row0 = blockIdx.x * 64;

    // ---- staging coords: thread t -> row t/4, 16-float segment t%4
    int srow = tid >> 2;                 // 0..63
    int sseg = tid & 3;                  // 0..3
    int gsrow = row0 + srow;
    if (gsrow >= nn) gsrow = nn - 1;
    const float4* sx = (const float4*)(x + (size_t)gsrow * NFEAT) + sseg * 4;
    int sslot = sseg * 2;                // logical 16B slot (0,2,4,6)
    int sr7 = srow & 7;

    // ---- compute coords
    int crow0 = (w & 1) * 32 + rfrag;
    int col0 = (w >> 1) * 64;
    int r0 = row0 + crow0;
    int r1 = r0 + 16;
    const __bf16* wb = WT + (size_t)(col0 + rfrag) * NFEAT + kg * 8;
    int cr7 = crow0 & 7;

    f32x4 acc0[4] = {};
    f32x4 acc1[4] = {};

    // ---- prologue: stage chunk 0 into buffer 0
    {
        float4 f0 = sx[0], f1 = sx[1], f2 = sx[2], f3 = sx[3];
        bf16x8 h0, h1;
        h0[0] = (__bf16)f0.x; h0[1] = (__bf16)f0.y; h0[2] = (__bf16)f0.z; h0[3] = (__bf16)f0.w;
        h0[4] = (__bf16)f1.x; h0[5] = (__bf16)f1.y; h0[6] = (__bf16)f1.z; h0[7] = (__bf16)f1.w;
        h1[0] = (__bf16)f2.x; h1[1] = (__bf16)f2.y; h1[2] = (__bf16)f2.z; h1[3] = (__bf16)f2.w;
        h1[4] = (__bf16)f3.x; h1[5] = (__bf16)f3.y; h1[6] = (__bf16)f3.z; h1[7] = (__bf16)f3.w;
        *(bf16x8*)&xs[0][srow][(sslot ^ sr7) * 8]       = h0;
        *(bf16x8*)&xs[0][srow][((sslot + 1) ^ sr7) * 8] = h1;
    }
    __syncthreads();

#pragma unroll
    for (int c = 0; c < 4; ++c) {
        const int cur = c & 1;

        float4 f0, f1, f2, f3;
        if (c < 3) {
            const float4* p = sx + (c + 1) * 16;
            f0 = p[0]; f1 = p[1]; f2 = p[2]; f3 = p[3];
        }

#pragma unroll
        for (int ks = 0; ks < 2; ++ks) {
            int slog = ks * 4 + kg;
            bf16x8 af0 = *(const bf16x8*)&xs[cur][crow0][(slog ^ cr7) * 8];
            bf16x8 af1 = *(const bf16x8*)&xs[cur][crow0 + 16][(slog ^ cr7) * 8];
            int koff = c * 64 + ks * 32;
#pragma unroll
            for (int nt = 0; nt < 4; ++nt) {
                bf16x8 bf = *(const bf16x8*)(wb + (size_t)nt * 16 * NFEAT + koff);
                acc0[nt] = __builtin_amdgcn_mfma_f32_16x16x32_bf16(bf, af0, acc0[nt], 0, 0, 0);
                acc1[nt] = __builtin_amdgcn_mfma_f32_16x16x32_bf16(bf, af1, acc1[nt], 0, 0, 0);
            }
        }

        if (c < 3) {
            bf16x8 h0, h1;
            h0[0] = (__bf16)f0.x; h0[1] = (__bf16)f0.y; h0[2] = (__bf16)f0.z; h0[3] = (__bf16)f0.w;
            h0[4] = (__bf16)f1.x; h0[5] = (__bf16)f1.y; h0[6] = (__bf16)f1.z; h0[7] = (__bf16)f1.w;
            h1[0] = (__bf16)f2.x; h1[1] = (__bf16)f2.y; h1[2] = (__bf16)f2.z; h1[3] = (__bf16)f2.w;
            h1[4] = (__bf16)f3.x; h1[5] = (__bf16)f3.y; h1[6] = (__bf16)f3.z; h1[7] = (__bf16)f3.w;
            *(bf16x8*)&xs[cur ^ 1][srow][(sslot ^ sr7) * 8]       = h0;
            *(bf16x8*)&xs[cur ^ 1][srow][((sslot + 1) ^ sr7) * 8] = h1;
        }
        __syncthreads();
    }

    if (r0 < nn) {
        float d = dinv[r0];
        __bf16* orow = xwb + (size_t)r0 * NHID + col0 + kg * 4;
#pragma unroll
        for (int nt = 0; nt < 4; ++nt) {
            bf16x4 v;
            v[0] = (__bf16)(acc0[nt][0] * d);
            v[1] = (__bf16)(acc0[nt][1] * d);
            v[2] = (__bf16)(acc0[nt][2] * d);
            v[3] = (__bf16)(acc0[nt][3] * d);
            *(bf16x4*)&orow[nt * 16] = v;
        }
    }
    if (r1 < nn) {
        float d = dinv[r1];
        __bf16* orow = xwb + (size_t)r1 * NHID + col0 + kg * 4;
#pragma unroll
        for (int nt = 0; nt < 4; ++nt) {
            bf16x4 v;
            v[0] = (__bf16)(acc1[nt][0] * d);
            v[1] = (__bf16)(acc1[nt][1] * d);
            v[2] = (__bf16)(acc1[nt][2] * d);
            v[3] = (__bf16)(acc1[nt][3] * d);
            *(bf16x4*)&orow[nt * 16] = v;
        }
    }
}

// ---------------------------------------------------------------------------
// 9) Gather + finalize v3: QUARTER-WAVE per node (16 lanes x 16B = 256B row).
//    Each 64-lane load instr carries 4 rows (1KB) -> 2x bytes in flight.
//    Unroll-4: 4KB in flight per wave during row phase.
// ---------------------------------------------------------------------------
__global__ __launch_bounds__(256) void gather_kernel(const uint4* __restrict__ xb4,
                                                     const int* __restrict__ base,
                                                     const int* __restrict__ cnt,
                                                     const int* __restrict__ ebuf,
                                                     const float* __restrict__ dinv,
                                                     const float* __restrict__ bias,
                                                     const float* __restrict__ pa,
                                                     float* __restrict__ out, int n) {
    int tid = threadIdx.x;
    int sub = tid & 15;                               // sublane in quarter-wave
    int node = (blockIdx.x * 256 + tid) >> 4;         // one node per 16 lanes
    if (node >= n) return;

    int b = base[node];
    int deg = cnt[node];

    // self loop: 16B of row `node` -> 8 bf16 elements
    uint4 s0 = xb4[(size_t)node * 16 + sub];
    float a0 = __uint_as_float(s0.x << 16);
    float a1 = __uint_as_float(s0.x & 0xffff0000u);
    float a2 = __uint_as_float(s0.y << 16);
    float a3 = __uint_as_float(s0.y & 0xffff0000u);
    float a4 = __uint_as_float(s0.z << 16);
    float a5 = __uint_as_float(s0.z & 0xffff0000u);
    float a6 = __uint_as_float(s0.w << 16);
    float a7 = __uint_as_float(s0.w & 0xffff0000u);

    int k = 0;
    for (; k + 4 <= deg; k += 4) {
        int r0 = ebuf[b + k + 0];
        int r1 = ebuf[b + k + 1];
        int r2 = ebuf[b + k + 2];
        int r3 = ebuf[b + k + 3];
        uint4 v0 = xb4[(size_t)r0 * 16 + sub];
        uint4 v1 = xb4[(size_t)r1 * 16 + sub];
        uint4 v2 = xb4[(size_t)r2 * 16 + sub];
        uint4 v3 = xb4[(size_t)r3 * 16 + sub];
        a0 += __uint_as_float(v0.x << 16) + __uint_as_float(v1.x << 16)
            + __uint_as_float(v2.x << 16) + __uint_as_float(v3.x << 16);
        a1 += __uint_as_float(v0.x & 0xffff0000u) + __uint_as_float(v1.x & 0xffff0000u)
            + __uint_as_float(v2.x & 0xffff0000u) + __uint_as_float(v3.x & 0xffff0000u);
        a2 += __uint_as_float(v0.y << 16) + __uint_as_float(v1.y << 16)
            + __uint_as_float(v2.y << 16) + __uint_as_float(v3.y << 16);
        a3 += __uint_as_float(v0.y & 0xffff0000u) + __uint_as_float(v1.y & 0xffff0000u)
            + __uint_as_float(v2.y & 0xffff0000u) + __uint_as_float(v3.y & 0xffff0000u);
        a4 += __uint_as_float(v0.z << 16) + __uint_as_float(v1.z << 16)
            + __uint_as_float(v2.z << 16) + __uint_as_float(v3.z << 16);
        a5 += __uint_as_float(v0.z & 0xffff0000u) + __uint_as_float(v1.z & 0xffff0000u)
            + __uint_as_float(v2.z & 0xffff0000u) + __uint_as_float(v3.z & 0xffff0000u);
        a6 += __uint_as_float(v0.w << 16) + __uint_as_float(v1.w << 16)
            + __uint_as_float(v2.w << 16) + __uint_as_float(v3.w << 16);
        a7 += __uint_as_float(v0.w & 0xffff0000u) + __uint_as_float(v1.w & 0xffff0000u)
            + __uint_as_float(v2.w & 0xffff0000u) + __uint_as_float(v3.w & 0xffff0000u);
    }
    for (; k < deg; ++k) {
        int r = ebuf[b + k];
        uint4 v = xb4[(size_t)r * 16 + sub];
        a0 += __uint_as_float(v.x << 16);
        a1 += __uint_as_float(v.x & 0xffff0000u);
        a2 += __uint_as_float(v.y << 16);
        a3 += __uint_as_float(v.y & 0xffff0000u);
        a4 += __uint_as_float(v.z << 16);
        a5 += __uint_as_float(v.z & 0xffff0000u);
        a6 += __uint_as_float(v.w << 16);
        a7 += __uint_as_float(v.w & 0xffff0000u);
    }

    float s = dinv[node];
    float alpha = pa[0];
    const float4* bb4 = (const float4*)bias;
    float4 b0 = bb4[sub * 2], b1 = bb4[sub * 2 + 1];
    float o0 = s * a0 + b0.x;
    float o1 = s * a1 + b0.y;
    float o2 = s * a2 + b0.z;
    float o3 = s * a3 + b0.w;
    float o4 = s * a4 + b1.x;
    float o5 = s * a5 + b1.y;
    float o6 = s * a6 + b1.z;
    float o7 = s * a7 + b1.w;
    o0 = o0 > 0.f ? o0 : alpha * o0;
    o1 = o1 > 0.f ? o1 : alpha * o1;
    o2 = o2 > 0.f ? o2 : alpha * o2;
    o3 = o3 > 0.f ? o3 : alpha * o3;
    o4 = o4 > 0.f ? o4 : alpha * o4;
    o5 = o5 > 0.f ? o5 : alpha * o5;
    o6 = o6 > 0.f ? o6 : alpha * o6;
    o7 = o7 > 0.f ? o7 : alpha * o7;
    float4* orow = (float4*)out + (size_t)node * 32 + sub * 2;
    orow[0] = make_float4(o0, o1, o2, o3);
    orow[1] = make_float4(o4, o5, o6, o7);
}

// ---------------------------------------------------------------------------
extern "C" void kernel_launch(void* const* d_in, const int* in_sizes, int n_in,
                              void* d_out, int out_size, void* d_ws, size_t ws_size,
                              hipStream_t stream) {
    const float* x    = (const float*)d_in[0];
    const int*   ei   = (const int*)d_in[1];   // int32, [2,E] row-major
    const float* W    = (const float*)d_in[2];
    const float* bias = (const float*)d_in[3];
    const float* pa   = (const float*)d_in[4];
    const float* u    = (const float*)d_in[5];

    int n = in_sizes[0] / NFEAT;     // 100000
    int e = in_sizes[1] / 2;         // 1600000
    const int* erow = ei;            // sources
    const int* ecol = ei + e;        // targets

    float* out = (float*)d_out;
    char* ws = (char*)d_ws;
    // workspace layout (bytes)
    float*        scal   = (float*)(ws);                    // 4 B
    int*          btot   = (int*)  (ws + 0x0001000);        // 392 ints
    int*          bbase  = (int*)  (ws + 0x0002000);        // 392 ints
    __bf16*       WT     = (__bf16*)(ws + 0x0010000);       // 64 KB
    int*          base_g = (int*)  (ws + 0x0100000);        // 400 KB
    int*          cnt_g  = (int*)  (ws + 0x0200000);        // 400 KB
    float*        dinv   = (float*)(ws + 0x0300000);        // 400 KB
    int*          blkhist= (int*)  (ws + 0x0400000);        // 611 KB
    unsigned int* rbuf   = (unsigned int*)(ws + 0x0500000); // 6.4 MB
    int*          ebuf   = (int*)  (ws + 0x0C00000);        // 6.4 MB
    __bf16*       xwb    = (__bf16*)(ws + 0x1300000);       // 25.6 MB

    sigma_kernel<<<1, 256, 0, stream>>>(W, u, scal);
    wt_kernel<<<(NFEAT * NHID) / 256, 256, 0, stream>>>(W, scal, WT);

    hist_kernel<<<NBLK, 256, 0, stream>>>(ecol, blkhist, e);
    scan_rows_kernel<<<(NBK + 3) / 4, 256, 0, stream>>>(blkhist, btot);
    scan_buckets_kernel<<<1, 512, 0, stream>>>(btot, bbase);
    coarse_scatter_kernel<<<NBLK, 512, 0, stream>>>(erow, ecol, blkhist, bbase, rbuf, e);
    fine_kernel<<<NBK, 256, 0, stream>>>(rbuf, bbase, base_g, cnt_g, dinv, ebuf, n);

    gemm_mfma_kernel<<<(n + 63) / 64, 256, 0, stream>>>(x, WT, dinv, xwb, n);

    long long gunits = (long long)n * 16;
    gather_kernel<<<(int)((gunits + 255) / 256), 256, 0, stream>>>(
        (const uint4*)xwb, base_g, cnt_g, ebuf, dinv, bias, pa, out, n);
}